// Round 5
// baseline (150.606 us; speedup 1.0000x reference)
//
#include <hip/hip_runtime.h>
#include <math.h>

// HiPPO-LegS reconstruction: out = sum_{k=1..256} coef[k-1]*sqrt(2k+1)*P_k(x),
// x = 2t/curr_t - 1.
//
// Model (fit R1-R10): dur_us = harness floor (~58.5us this container: 268MB
// ws re-poison fills @ ~41us, 82% HBM peak) + kernel. R7 anchor (1pt/thread,
// launch_bounds(256,8)): 63.6us total -> kernel ~5.1us. Fitted: kernel is
// DS-pipe-bound -- 2048 broadcast ds_read_b128/CU x ~6.3cy = 12.9K cyc,
// vs 8192-cyc VALU window (512 v_fma x 2cy x 8 waves/SIMD).
//
// R9 SPILL POST-MORTEM: spill is driven by the scheduler's occupancy-
// dependent hoist appetite, not raw reg demand. At launch_bounds(.,4)
// (cap 128) it hoists ~40 ds_reads -> spills 146MB/dispatch, kernel 50us.
// At (.,8) (cap 64) it keeps the window tight -> no spill (proven R7/R10).
//
// R11: 2pt/thread + launch_bounds(256,8) -- the untested safe cell. DS ops
// per CU halve (1024 x 6.3 = 6.5K cyc < 8192 VALU window -> DS unbinds);
// VALU floor unchanged at 3.4us; cap-64 keeps hoist tight. 1024 blocks =
// 4 blocks/CU, 4 waves/SIMD residency, 2 chains/thread = 8-deep ILP/SIMD.
// Predict kernel ~3.6-4.0us, dur_us 61.5-62.5. Failure signatures: dur>70 +
// hippo in top-5 with WRITE_SIZE blowup = spill recurred (revert to R7).
//
//   Clenshaw on rescaled basis S_{d+1} = 2x*S_d - beta_d*S_{d-1}:
//   b_k = w'_k + 2x*b_{k+1} - beta_{k+1}*b_{k+2};  f = x*b_1 - (2/3)*b_2
//   beta_d = 4d^2/(4d^2-1) (compile-time), w'_k = coef[k-1]*sqrt(2k+1)*g_k

#define NDEG 256

// g_i = 2*C(2i,i)/4^i: exact for i<8, 4-term Stirling beyond (rel < 1e-7).
__device__ __forceinline__ float g_of(int i) {
    const float fi = (float)i;
    float r = 2.0f * rsqrtf(3.14159265358979f * fi);
    float inv = 1.0f / fi;
    float corr = 1.0f + inv * (-0.125f + inv * (0.0078125f + inv * 0.0048828125f));
    float g = r * corr;
    g = (i == 1) ? 1.0f          : g;
    g = (i == 2) ? 0.75f         : g;
    g = (i == 3) ? 0.625f        : g;
    g = (i == 4) ? 0.546875f     : g;
    g = (i == 5) ? 0.4921875f    : g;
    g = (i == 6) ? 0.451171875f  : g;
    g = (i == 7) ? 0.4189453125f : g;
    return g;
}

// -beta_{d} as a compile-time-foldable constant.
constexpr float nbeta(int d) {
    double dd = (double)d;
    return (float)(-(4.0 * dd * dd) / (4.0 * dd * dd - 1.0));
}

// One Clenshaw degree for 2 independent points. nb lands in an SGPR (one
// s_mov, co-issued) so t_p = fma(nb,b2_p,w) is VOP3 v_fma; n_p = fma(U,b1,t)
// is VOP2 v_fmac. 4 FMAs with 2-way ILP; b-renames vanish under full unroll.
__device__ __forceinline__ void step2(
    const float U0, const float U1,
    float& b10, float& b20, float& b11, float& b21,
    const float nb, const float w)
{
    float t0 = fmaf(nb, b20, w);
    float t1 = fmaf(nb, b21, w);
    float n0 = fmaf(U0, b10, t0);
    float n1 = fmaf(U1, b11, t1);
    b20 = b10; b21 = b11;
    b10 = n0;  b11 = n1;
}

#define STEP2(NB, W) step2(U0, U1, b10, b20, b11, b21, (NB), (W))

__global__ __launch_bounds__(256, 8) void hippo_kernel(
    const float* __restrict__ t,
    const float* __restrict__ coef,
    const int* __restrict__ curr_t,
    float* __restrict__ out,
    int n)
{
    // w'[k], k=1..256: w4[j] = {w'(4j+1), w'(4j+2), w'(4j+3), w'(4j+4)}
    __shared__ float4 w4[NDEG / 4];
    float* wf = (float*)w4;

    const int tid = threadIdx.x;
    {
        const int k = tid + 1;
        wf[tid] = coef[tid] * sqrtf(2.0f * (float)k + 1.0f) * g_of(k);
    }
    __syncthreads();

    const int gid  = blockIdx.x * 256 + tid;  // float2-group index
    const int base = gid * 2;
    const float s = 2.0f / (float)curr_t[0];

    float2 tv;
    if (base + 1 < n) {
        tv = reinterpret_cast<const float2*>(t)[gid];
    } else {  // tail safety (never taken at n=524288)
        tv.x = (base + 0 < n) ? t[base + 0] : 0.0f;
        tv.y = 0.0f;
    }

    const float x0 = fmaf(tv.x, s, -1.0f);
    const float x1 = fmaf(tv.y, s, -1.0f);
    const float U0 = 2.0f * x0;
    const float U1 = 2.0f * x1;

    float b10 = 0.0f, b20 = 0.0f;   // b_258 = b_257 = 0, per point
    float b11 = 0.0f, b21 = 0.0f;

#pragma unroll
    for (int j = 63; j >= 0; --j) {
        const float4 c = w4[j];   // broadcast ds_read_b128, 1 per 4 degrees
        STEP2(nbeta(4 * j + 5), c.w);  // degree 4j+4
        STEP2(nbeta(4 * j + 4), c.z);  // degree 4j+3
        STEP2(nbeta(4 * j + 3), c.y);  // degree 4j+2
        STEP2(nbeta(4 * j + 2), c.x);  // degree 4j+1
    }

    // f = x*b_1 - beta_1*S_0*b_2 = x*b1 - (4/3)*(1/2)*b2
    float2 ov;
    ov.x = fmaf(x0, b10, -0.66666666666667f * b20);
    ov.y = fmaf(x1, b11, -0.66666666666667f * b21);

    if (base + 1 < n) {
        reinterpret_cast<float2*>(out)[gid] = ov;
    } else if (base < n) {
        out[base] = ov.x;
    }
}

extern "C" void kernel_launch(void* const* d_in, const int* in_sizes, int n_in,
                              void* d_out, int out_size, void* d_ws, size_t ws_size,
                              hipStream_t stream)
{
    const float* t      = (const float*)d_in[0];
    const float* coef   = (const float*)d_in[1];
    const int*   curr_t = (const int*)d_in[2];
    float*       out    = (float*)d_out;

    int n = in_sizes[0];                   // 524288
    int blocks = (n + 511) / 512;          // 1024 blocks = 4 blocks/CU
    hippo_kernel<<<blocks, 256, 0, stream>>>(t, coef, curr_t, out, n);
}

// Round 6
// 63.460 us; speedup vs baseline: 2.3732x; 2.3732x over previous
//
#include <hip/hip_runtime.h>
#include <math.h>

// HiPPO-LegS reconstruction: out = sum_{k=1..256} coef[k-1]*sqrt(2k+1)*P_k(x),
// x = 2t/curr_t - 1.
//
// Model (fit R1-R11): dur_us = harness floor (~58.5us: 268MB ws re-poison
// fills @ ~41us, 82% HBM peak; drifts a few us across containers) + kernel.
// This kernel (R7 shape): kernel ~5.1us vs 3.4us VALU-issue floor
// (512 FMA/pt; Clenshaw = 2 ops/degree is op-minimal, monomial Horner
// overflows fp32). Contestable slice <= 1.7us = ~2.7% of dur_us.
//
// SPILL MATRIX (do not re-enter the failed cells):
//   1pt/thread + launch_bounds(256,8)  -> NO spill, kernel ~5.1us  [R7/R10]
//   4pt/thread + launch_bounds(256,2)  -> no spill                 [R8]
//   2pt/thread + launch_bounds(256,4)  -> 146MB scratch, 50us      [R9]
//   2pt/thread + launch_bounds(256,8)  -> 233MB scratch, ~115us    [R11]
// Mechanism: under full unroll the machine scheduler hoists the 64
// ds_read_b128s with a shape-dependent appetite; for the 2pt float2 shape
// the window exceeds the cap and the allocator SPILLS it (912B/thread)
// instead of shortening it. Register-cap knobs do not control this; only
// the proven shapes do. DS-free alternative (s_load coef + 3 ops/degree)
// computes to the same ~12.3K cyc/CU window -- no headroom there either.
//
//   Clenshaw on rescaled basis S_{d+1} = 2x*S_d - beta_d*S_{d-1}:
//   b_k = w'_k + 2x*b_{k+1} - beta_{k+1}*b_{k+2};  f = x*b_1 - (2/3)*b_2
//   beta_d = 4d^2/(4d^2-1) (compile-time), w'_k = coef[k-1]*sqrt(2k+1)*g_k

#define NDEG 256

// g_i = 2*C(2i,i)/4^i: exact for i<8, 4-term Stirling beyond (rel < 1e-7).
__device__ __forceinline__ float g_of(int i) {
    const float fi = (float)i;
    float r = 2.0f * rsqrtf(3.14159265358979f * fi);
    float inv = 1.0f / fi;
    float corr = 1.0f + inv * (-0.125f + inv * (0.0078125f + inv * 0.0048828125f));
    float g = r * corr;
    g = (i == 1) ? 1.0f          : g;
    g = (i == 2) ? 0.75f         : g;
    g = (i == 3) ? 0.625f        : g;
    g = (i == 4) ? 0.546875f     : g;
    g = (i == 5) ? 0.4921875f    : g;
    g = (i == 6) ? 0.451171875f  : g;
    g = (i == 7) ? 0.4189453125f : g;
    return g;
}

// -beta_{d} as a compile-time-foldable constant.
constexpr float nbeta(int d) {
    double dd = (double)d;
    return (float)(-(4.0 * dd * dd) / (4.0 * dd * dd - 1.0));
}

// One Clenshaw degree: b_K = w + 2x*b1 - beta_{K+1}*b2.
// Shaped so both ops are v_fmac_f32 (VOP2, literal nb inline in src0).
__device__ __forceinline__ void step(const float U, float& b1, float& b2,
                                     const float nb, const float w) {
    float tt = fmaf(nb, b2, w);   // v_fmac: tt(=w) += nb*b2
    float bn = fmaf(U, b1, tt);   // v_fmac: tt += U*b1
    b2 = b1;
    b1 = bn;
}

__global__ __launch_bounds__(256, 8) void hippo_kernel(
    const float* __restrict__ t,
    const float* __restrict__ coef,
    const int* __restrict__ curr_t,
    float* __restrict__ out,
    int n)
{
    // w'[k], k=1..256: w4[j] = {w'(4j+1), w'(4j+2), w'(4j+3), w'(4j+4)}
    __shared__ float4 w4[NDEG / 4];
    float* wf = (float*)w4;

    const int tid = threadIdx.x;
    {
        const int k = tid + 1;
        wf[tid] = coef[tid] * sqrtf(2.0f * (float)k + 1.0f) * g_of(k);
    }
    __syncthreads();

    const int gid = blockIdx.x * 256 + tid;
    const float s = 2.0f / (float)curr_t[0];
    const float x = fmaf(t[gid < n ? gid : 0], s, -1.0f);  // x = 2t/curr_t - 1
    const float U = 2.0f * x;

    float b1 = 0.0f, b2 = 0.0f;   // b_258 = b_257 = 0
#pragma unroll
    for (int j = 63; j >= 0; --j) {
        const float4 c = w4[j];   // broadcast ds_read_b128, scheduler-managed
        step(U, b1, b2, nbeta(4 * j + 5), c.w);  // degree 4j+4
        step(U, b1, b2, nbeta(4 * j + 4), c.z);  // degree 4j+3
        step(U, b1, b2, nbeta(4 * j + 3), c.y);  // degree 4j+2
        step(U, b1, b2, nbeta(4 * j + 2), c.x);  // degree 4j+1
    }

    // f = x*b_1 - beta_1*S_0*b_2 = x*b1 - (4/3)*(1/2)*b2
    if (gid < n)
        out[gid] = fmaf(x, b1, -0.66666666666667f * b2);
}

extern "C" void kernel_launch(void* const* d_in, const int* in_sizes, int n_in,
                              void* d_out, int out_size, void* d_ws, size_t ws_size,
                              hipStream_t stream)
{
    const float* t      = (const float*)d_in[0];
    const float* coef   = (const float*)d_in[1];
    const int*   curr_t = (const int*)d_in[2];
    float*       out    = (float*)d_out;

    int n = in_sizes[0];                 // 524288
    int blocks = (n + 255) / 256;        // 2048 blocks -> 8 waves/SIMD
    hippo_kernel<<<blocks, 256, 0, stream>>>(t, coef, curr_t, out, n);
}